// Round 3
// baseline (2726.999 us; speedup 1.0000x reference)
//
#include <hip/hip_runtime.h>
#include <hip/hip_bf16.h>
#include <math.h>

// FactorizedVectorQuantizer for MI355X (gfx950) — R3: LDS-staged x.
//
// rows = 32768, feat 256 = 128 shape + 128 color; codebooks 8192x128, 512x128.
// Bit-exact numpy pipeline: D = fmaf(-2, dot, S + t); dot & S are single
// serial ascending-k fp32 FMA chains; argmin strict-< ascending index.
//
// argmin_k: block = 128 rows (64KB LDS, XOR-swizzled for conflict-free
// ds_read_b128) x 1024 codes (shape) / 512 (color), 256 thr = row x 2 halves.
// w/t wave-uniform -> s_load (readfirstlane on half). 8 codes in flight:
// 1 ds_read_b128 per 32 FMAs. x quad prefetched 1 iter ahead.

#define NROWS   32768
#define NSHAPE  8192
#define NCOLOR  512
#define HALF    128

#define ROWS_PB 128
#define NPS     16          // shape partials per row (8 chunks x 2 halves)
#define NPC     2           // color partials per row
#define NSHAPE_BLKS 2048    // 256 rowblks x 8 chunks
#define NCOLOR_BLKS 256
#define NBLKS   (NSHAPE_BLKS + NCOLOR_BLKS)   // 2304, divisible by 8

// workspace byte offsets
#define OFF_TS    0u                                  // f32[8192]
#define OFF_TC    32768u                              // f32[512]
#define OFF_CNT_S 34816u                              // u32[8192]
#define OFF_CNT_C 67584u                              // u32[512]
#define OFF_LOSS  69632u                              // double
#define OFF_PVS   69648u                              // f32[NROWS*NPS]
#define OFF_PIS   (OFF_PVS + NROWS*NPS*4u)            // i32[NROWS*NPS]
#define OFF_PVC   (OFF_PIS + NROWS*NPS*4u)            // f32[NROWS*NPC]
#define OFF_PIC   (OFF_PVC + NROWS*NPC*4u)            // i32[NROWS*NPC]

__global__ __launch_bounds__(256) void codes_sq_k(
    const float* __restrict__ Ws, const float* __restrict__ Wc,
    float* __restrict__ ts, float* __restrict__ tc)
{
    int j = blockIdx.x * 256 + threadIdx.x;
    if (j < NSHAPE) {
        const float* w = Ws + (size_t)j * HALF;
        float s = 0.f;
        #pragma unroll
        for (int k = 0; k < HALF; ++k) s = fmaf(w[k], w[k], s);
        ts[j] = s;
    } else if (j - NSHAPE < NCOLOR) {
        int jc = j - NSHAPE;
        const float* w = Wc + (size_t)jc * HALF;
        float s = 0.f;
        #pragma unroll
        for (int k = 0; k < HALF; ++k) s = fmaf(w[k], w[k], s);
        tc[jc] = s;
    }
}

__global__ __launch_bounds__(256, 2) void argmin_k(
    const float* __restrict__ input,
    const float* __restrict__ Ws, const float* __restrict__ Wc,
    const float* __restrict__ ts, const float* __restrict__ tc,
    float* __restrict__ pvs, int* __restrict__ pis,
    float* __restrict__ pvc, int* __restrict__ pic)
{
    __shared__ float xs[ROWS_PB * HALF];   // 64 KB, XOR-swizzled

    int d = blockIdx.x;
    // XCD co-location: the 8 chunk-blocks sharing one x-tile land on one XCD
    int o = (d & 7) * (NBLKS / 8) + (d >> 3);
    int tid = threadIdx.x;

    const float* W; const float* tv; float* pv; int* pi;
    int rowblk, codebase, ncth, np, featoff, pbase;
    if (o < NSHAPE_BLKS) {
        rowblk = o >> 3;
        int chunk = o & 7;
        codebase = chunk << 10;     // 1024 codes per chunk-block
        ncth = 512;                 // codes per thread (half)
        np = NPS; featoff = 0; pbase = chunk << 1;
        W = Ws; tv = ts; pv = pvs; pi = pis;
    } else {
        rowblk = o - NSHAPE_BLKS;
        codebase = 0; ncth = 256; np = NPC; featoff = HALF; pbase = 0;
        W = Wc; tv = tc; pv = pvc; pi = pic;
    }
    // wave-uniform by construction; readfirstlane makes it provably so
    int half = __builtin_amdgcn_readfirstlane(tid >> 7);

    // ---- stage 128 rows x 128 feats into LDS (coalesced global reads) ----
    int r0 = rowblk * ROWS_PB;
    int b = r0 >> 10, hw0 = r0 & 1023;
    const float* __restrict__ base =
        input + ((size_t)b << 18) + ((size_t)featoff << 10) + hw0;
    #pragma unroll
    for (int i = 0; i < 64; ++i) {
        int idx = tid + (i << 8);
        int row = idx & 127, k = idx >> 7;
        float v = base[((size_t)k << 10) + row];
        xs[(row << 7) + ((((k >> 2) ^ (row & 31)) << 2) | (k & 3))] = v;
    }
    __syncthreads();

    int row = tid & 127;
    int sw = row & 31;
    const float* __restrict__ xr = &xs[row << 7];

    // ---- S: serial ascending-k FMA chain (same order as passing R1) ----
    float S = 0.f;
    #pragma unroll
    for (int kq = 0; kq < 32; ++kq) {
        const float4 q = *(const float4*)&xr[(kq ^ sw) << 2];
        S = fmaf(q.x, q.x, S); S = fmaf(q.y, q.y, S);
        S = fmaf(q.z, q.z, S); S = fmaf(q.w, q.w, S);
    }

    int cb = codebase + half * ncth;                // wave-uniform
    const float* __restrict__ Wb = W + ((size_t)cb << 7);
    const float* __restrict__ tb = tv + cb;

    float best = INFINITY; int bestj = 0;
    int ng = ncth >> 3;   // groups of 8 codes
    for (int g = 0; g < ng; ++g) {
        const float* __restrict__ wg = Wb + ((size_t)g << 10); // g*8*128
        float acc[8] = {0.f,0.f,0.f,0.f,0.f,0.f,0.f,0.f};

        float4 xq = *(const float4*)&xr[(0 ^ sw) << 2];
        #pragma unroll
        for (int kq = 0; kq < 32; ++kq) {
            float4 xn = xq;
            if (kq < 31) xn = *(const float4*)&xr[((kq + 1) ^ sw) << 2];
            const float* __restrict__ wk = wg + (kq << 2);
            // serial ascending k per (row,code); 8 chains for ILP
            #pragma unroll
            for (int kk = 0; kk < 4; ++kk) {
                float xv = (kk == 0) ? xq.x : (kk == 1) ? xq.y
                         : (kk == 2) ? xq.z : xq.w;
                #pragma unroll
                for (int c = 0; c < 8; ++c)
                    acc[c] = fmaf(xv, wk[c * HALF + kk], acc[c]);
            }
            xq = xn;
        }
        #pragma unroll
        for (int c = 0; c < 8; ++c) {
            float Sp = S + tb[(g << 3) + c];
            float D = fmaf(-2.0f, acc[c], Sp);   // == Sp - 2*a bitwise
            if (D < best) { best = D; bestj = (g << 3) + c; }
        }
    }

    int r = r0 + row;
    int p = pbase + half;
    pv[(size_t)r * np + p] = best;
    pi[(size_t)r * np + p] = cb + bestj;
}

__global__ __launch_bounds__(256) void finalize_k(
    const float* __restrict__ input,
    const float* __restrict__ Ws, const float* __restrict__ Wc,
    const float* __restrict__ pvs, const int* __restrict__ pis,
    const float* __restrict__ pvc, const int* __restrict__ pic,
    unsigned* __restrict__ cnt_s, unsigned* __restrict__ cnt_c,
    double* __restrict__ loss_sum, float* __restrict__ out)
{
    int tid = threadIdx.x;
    int r = blockIdx.x * 256 + tid;

    // reduce partials, strict < ascending p => global lowest-index argmin
    float bv = INFINITY; int bi = 0;
    #pragma unroll
    for (int c = 0; c < NPS; ++c) {
        float v = pvs[(size_t)r * NPS + c];
        int ix = pis[(size_t)r * NPS + c];
        if (v < bv) { bv = v; bi = ix; }
    }
    float cv = INFINITY; int ci = 0;
    #pragma unroll
    for (int c = 0; c < NPC; ++c) {
        float v = pvc[(size_t)r * NPC + c];
        int ix = pic[(size_t)r * NPC + c];
        if (v < cv) { cv = v; ci = ix; }
    }
    atomicAdd(&cnt_s[bi], 1u);
    atomicAdd(&cnt_c[ci], 1u);

    int b = r >> 10; int hw = r & 1023;
    const float* __restrict__ xin = input + ((size_t)b << 18) + hw;
    float* __restrict__ op = out + ((size_t)b << 18) + hw;
    const float* __restrict__ qs = Ws + ((size_t)bi << 7);
    const float* __restrict__ qc = Wc + ((size_t)ci << 7);

    double ls = 0.0;
    #pragma unroll 8
    for (int c = 0; c < HALF; ++c) {
        float f = xin[(size_t)c << 10];
        float dd = qs[c] - f;                  // fp32(q - f)
        op[(size_t)c << 10] = f + dd;          // fp32(f + fp32(q - f))
        ls += (double)dd * (double)dd;
    }
    #pragma unroll 8
    for (int c = 0; c < HALF; ++c) {
        float f = xin[(size_t)(c + HALF) << 10];
        float dd = qc[c] - f;
        op[(size_t)(c + HALF) << 10] = f + dd;
        ls += (double)dd * (double)dd;
    }

    __shared__ double red[256];
    red[tid] = ls;
    __syncthreads();
    for (int s = 128; s > 0; s >>= 1) {
        if (tid < s) red[tid] += red[tid + s];
        __syncthreads();
    }
    if (tid == 0) atomicAdd(loss_sum, red[0]);
}

__global__ __launch_bounds__(256) void scalars_k(
    const unsigned* __restrict__ cnt_s, const unsigned* __restrict__ cnt_c,
    const double* __restrict__ loss_sum, float* __restrict__ out3)
{
    int tid = threadIdx.x;
    double es = 0.0, ec = 0.0;
    for (int j = tid; j < NSHAPE; j += 256) {
        float p = (float)cnt_s[j] / 32768.0f;
        es += (double)(p * logf(p + 1e-10f));
    }
    for (int j = tid; j < NCOLOR; j += 256) {
        float p = (float)cnt_c[j] / 32768.0f;
        ec += (double)(p * logf(p + 1e-10f));
    }
    __shared__ double r1[256], r2[256];
    r1[tid] = es; r2[tid] = ec;
    __syncthreads();
    for (int s = 128; s > 0; s >>= 1) {
        if (tid < s) { r1[tid] += r1[tid + s]; r2[tid] += r2[tid + s]; }
        __syncthreads();
    }
    if (tid == 0) {
        out3[0] = (float)(1.25 * loss_sum[0] / 8388608.0);  // q + 0.25*e latent
        out3[1] = expf(-(float)r1[0]);
        out3[2] = expf(-(float)r2[0]);
    }
}

extern "C" void kernel_launch(void* const* d_in, const int* in_sizes, int n_in,
                              void* d_out, int out_size, void* d_ws, size_t ws_size,
                              hipStream_t stream)
{
    const float* input = (const float*)d_in[0];
    const float* Ws    = (const float*)d_in[1];
    const float* Wc    = (const float*)d_in[2];
    float* out = (float*)d_out;
    char* ws = (char*)d_ws;

    float*    ts       = (float*)(ws + OFF_TS);
    float*    tc       = (float*)(ws + OFF_TC);
    unsigned* cnt_s    = (unsigned*)(ws + OFF_CNT_S);
    unsigned* cnt_c    = (unsigned*)(ws + OFF_CNT_C);
    double*   loss_sum = (double*)(ws + OFF_LOSS);
    float*    pvs      = (float*)(ws + OFF_PVS);
    int*      pis      = (int*)(ws + OFF_PIS);
    float*    pvc      = (float*)(ws + OFF_PVC);
    int*      pic      = (int*)(ws + OFF_PIC);

    // zero counts + loss accumulator (ws is 0xAA-poisoned once, not re-poisoned)
    hipMemsetAsync(ws + OFF_CNT_S, 0, (OFF_LOSS + 8u) - OFF_CNT_S, stream);

    codes_sq_k<<<(NSHAPE + NCOLOR + 255) / 256, 256, 0, stream>>>(Ws, Wc, ts, tc);

    argmin_k<<<NBLKS, 256, 0, stream>>>(
        input, Ws, Wc, ts, tc, pvs, pis, pvc, pic);

    finalize_k<<<NROWS / 256, 256, 0, stream>>>(
        input, Ws, Wc, pvs, pis, pvc, pic, cnt_s, cnt_c, loss_sum, out);

    scalars_k<<<1, 256, 0, stream>>>(cnt_s, cnt_c, loss_sum, out + 8388608);
}

// Round 4
// 923.161 us; speedup vs baseline: 2.9540x; 2.9540x over previous
//
#include <hip/hip_runtime.h>
#include <hip/hip_bf16.h>
#include <math.h>

// FactorizedVectorQuantizer MI355X (gfx950) — R4: LDS-tiled fp32 GEMM + argmin.
//
// rows 32768, feats 256 = 128 shape + 128 color; codebooks 8192x128, 512x128.
// Bit-exact numpy pipeline: D = fmaf(-2, dot, S + t); dot and S are single
// serial ascending-k fp32 FMA chains (R1-proven); argmin = lowest index on
// ties, implemented as min over packed u64 key (mono(D)<<32 | code).
//
// gemm_argmin_k: 128x128x128 block, BK=32 x 4 steps, 256 thr, 8x8 micro-tile
// as (4+4)x(4+4). 4 ds_read_b128 per 64 FMA -> VALU-bound. Cross-block argmin
// via global atomicMin(u64). XCD-swizzled rowblk-major grid for x-tile L2 reuse.

#define NROWS   32768
#define NSHAPE  8192
#define NCOLOR  512
#define HALF    128

#define NSB     16384               // 256 rowblks x 64 colblks (shape)
#define NCB     1024                // 256 rowblks x 4 colblks (color)
#define NBLKS   (NSB + NCB)         // 17408, divisible by 8

// workspace byte offsets
#define OFF_TS    0u                // f32[8192]
#define OFF_TC    32768u            // f32[512]
#define OFF_CNT_S 34816u            // u32[8192]
#define OFF_CNT_C 67584u            // u32[512]
#define OFF_LOSS  69632u            // double
#define OFF_SS    69648u            // f32[32768]
#define OFF_SC    200720u           // f32[32768]
#define OFF_BS    331792u           // u64[32768] packed best (shape)
#define OFF_BC    593936u           // u64[32768] packed best (color)
#define OFF_END   856080u

__device__ __forceinline__ unsigned mono_f32(float d) {
    unsigned u = __float_as_uint(d);
    return (u & 0x80000000u) ? ~u : (u | 0x80000000u);
}

__global__ __launch_bounds__(256) void codes_sq_k(
    const float* __restrict__ Ws, const float* __restrict__ Wc,
    float* __restrict__ ts, float* __restrict__ tc)
{
    int j = blockIdx.x * 256 + threadIdx.x;
    if (j < NSHAPE) {
        const float* w = Ws + (size_t)j * HALF;
        float s = 0.f;
        #pragma unroll
        for (int k = 0; k < HALF; ++k) s = fmaf(w[k], w[k], s);
        ts[j] = s;
    } else if (j - NSHAPE < NCOLOR) {
        int jc = j - NSHAPE;
        const float* w = Wc + (size_t)jc * HALF;
        float s = 0.f;
        #pragma unroll
        for (int k = 0; k < HALF; ++k) s = fmaf(w[k], w[k], s);
        tc[jc] = s;
    }
}

__global__ __launch_bounds__(256) void rows_sq_k(
    const float* __restrict__ input,
    float* __restrict__ Ss, float* __restrict__ Sc)
{
    int r = blockIdx.x * 256 + threadIdx.x;
    int b = r >> 10, hw = r & 1023;
    const float* __restrict__ xin = input + ((size_t)b << 18) + hw;
    float s = 0.f;
    #pragma unroll
    for (int k = 0; k < HALF; ++k) {
        float v = xin[(size_t)k << 10];
        s = fmaf(v, v, s);
    }
    Ss[r] = s;
    float s2 = 0.f;
    #pragma unroll
    for (int k = 0; k < HALF; ++k) {
        float v = xin[(size_t)(k + HALF) << 10];
        s2 = fmaf(v, v, s2);
    }
    Sc[r] = s2;
}

__global__ __launch_bounds__(256, 4) void gemm_argmin_k(
    const float* __restrict__ input,
    const float* __restrict__ Ws, const float* __restrict__ Wc,
    const float* __restrict__ ts, const float* __restrict__ tc,
    const float* __restrict__ Ss, const float* __restrict__ Sc,
    unsigned long long* __restrict__ bs, unsigned long long* __restrict__ bc)
{
    __shared__ __align__(16) char smem[32768];
    float (*xs)[HALF] = reinterpret_cast<float(*)[HALF]>(smem);          // [32][128]
    float (*wt)[HALF] = reinterpret_cast<float(*)[HALF]>(smem + 16384);  // [32][128]

    int d = blockIdx.x;
    int o = (d & 7) * (NBLKS / 8) + (d >> 3);   // bijective XCD swizzle

    int rowblk, c0, featoff;
    const float* W; const float* tv; const float* Sarr;
    unsigned long long* bestArr;
    if (o < NSB) {
        rowblk = o >> 6; c0 = (o & 63) << 7; featoff = 0;
        W = Ws; tv = ts; Sarr = Ss; bestArr = bs;
    } else {
        int o2 = o - NSB;
        rowblk = o2 >> 2; c0 = (o2 & 3) << 7; featoff = HALF;
        W = Wc; tv = tc; Sarr = Sc; bestArr = bc;
    }

    int tid = threadIdx.x;
    int tr = tid & 15, tcg = tid >> 4;
    int r0 = rowblk << 7;
    int b = r0 >> 10, hw0 = r0 & 1023;
    const float* __restrict__ xbase =
        input + ((size_t)b << 18) + ((size_t)featoff << 10) + hw0;
    const float* __restrict__ wbase = W + ((size_t)c0 << 7);

    float acc[8][8] = {{0.f}};

    for (int ks = 0; ks < 4; ++ks) {
        if (ks) __syncthreads();
        // ---- stage X: xs[k][row], coalesced 128B segments ----
        {
            int kl = tid >> 3, rq8 = tid & 7;
            const float* __restrict__ gp = xbase + ((size_t)((ks << 5) + kl) << 10);
            #pragma unroll
            for (int p = 0; p < 4; ++p) {
                int rq = rq8 + (p << 3);
                float4 v = *(const float4*)(gp + (rq << 2));
                *(float4*)&xs[kl][rq << 2] = v;
            }
            // ---- stage W transposed: wt[k][col] ----
            int cq = tid >> 3, k4 = tid & 7;
            #pragma unroll
            for (int q = 0; q < 4; ++q) {
                int c = (q << 5) + cq;
                float4 v = *(const float4*)(wbase + ((size_t)c << 7) + (ks << 5) + (k4 << 2));
                wt[(k4 << 2) + 0][c] = v.x;
                wt[(k4 << 2) + 1][c] = v.y;
                wt[(k4 << 2) + 2][c] = v.z;
                wt[(k4 << 2) + 3][c] = v.w;
            }
        }
        __syncthreads();
        // ---- compute 32 k: serial ascending-k FMA chains per acc[i][j] ----
        #pragma unroll 8
        for (int k = 0; k < 32; ++k) {
            float4 x0 = *(const float4*)&xs[k][tr << 2];
            float4 x1 = *(const float4*)&xs[k][64 + (tr << 2)];
            float4 w0 = *(const float4*)&wt[k][tcg << 2];
            float4 w1 = *(const float4*)&wt[k][64 + (tcg << 2)];
            float xv[8] = {x0.x, x0.y, x0.z, x0.w, x1.x, x1.y, x1.z, x1.w};
            float wv[8] = {w0.x, w0.y, w0.z, w0.w, w1.x, w1.y, w1.z, w1.w};
            #pragma unroll
            for (int i = 0; i < 8; ++i)
                #pragma unroll
                for (int j = 0; j < 8; ++j)
                    acc[i][j] = fmaf(xv[i], wv[j], acc[i][j]);
        }
    }

    // ---- epilogue: D = fmaf(-2, acc, S + t); packed argmin ----
    float Sr[8];
    #pragma unroll
    for (int i = 0; i < 8; ++i) {
        int rl = ((i & 4) << 4) + (tr << 2) + (i & 3);
        Sr[i] = Sarr[r0 + rl];
    }
    float tcl[8]; int cg[8];
    #pragma unroll
    for (int j = 0; j < 8; ++j) {
        int cl = ((j & 4) << 4) + (tcg << 2) + (j & 3);
        cg[j] = c0 + cl;
        tcl[j] = tv[cg[j]];
    }
    unsigned long long bestp[8];
    #pragma unroll
    for (int i = 0; i < 8; ++i) bestp[i] = ~0ull;
    #pragma unroll
    for (int j = 0; j < 8; ++j) {
        #pragma unroll
        for (int i = 0; i < 8; ++i) {
            float Sp = Sr[i] + tcl[j];
            float D = fmaf(-2.0f, acc[i][j], Sp);   // == Sp - 2*a bitwise
            unsigned long long p =
                ((unsigned long long)mono_f32(D) << 32) | (unsigned)cg[j];
            if (p < bestp[i]) bestp[i] = p;
        }
    }

    __syncthreads();   // done with xs/wt; reuse as reduction grid [128][17] u64
    unsigned long long* red = reinterpret_cast<unsigned long long*>(smem);
    #pragma unroll
    for (int i = 0; i < 8; ++i) {
        int rl = ((i & 4) << 4) + (tr << 2) + (i & 3);
        red[rl * 17 + tcg] = bestp[i];
    }
    __syncthreads();
    if (tid < 128) {
        unsigned long long m = red[tid * 17];
        #pragma unroll
        for (int q = 1; q < 16; ++q) {
            unsigned long long v = red[tid * 17 + q];
            if (v < m) m = v;
        }
        atomicMin(&bestArr[r0 + tid], m);
    }
}

__global__ __launch_bounds__(256) void finalize_k(
    const float* __restrict__ input,
    const float* __restrict__ Ws, const float* __restrict__ Wc,
    const unsigned long long* __restrict__ bs,
    const unsigned long long* __restrict__ bc,
    unsigned* __restrict__ cnt_s, unsigned* __restrict__ cnt_c,
    double* __restrict__ loss_sum, float* __restrict__ out)
{
    int tid = threadIdx.x;
    int r = blockIdx.x * 256 + tid;

    int bi = (int)(bs[r] & 0xFFFFFFFFu);
    int ci = (int)(bc[r] & 0xFFFFFFFFu);
    atomicAdd(&cnt_s[bi], 1u);
    atomicAdd(&cnt_c[ci], 1u);

    int b = r >> 10; int hw = r & 1023;
    const float* __restrict__ xin = input + ((size_t)b << 18) + hw;
    float* __restrict__ op = out + ((size_t)b << 18) + hw;
    const float* __restrict__ qs = Ws + ((size_t)bi << 7);
    const float* __restrict__ qc = Wc + ((size_t)ci << 7);

    double ls = 0.0;
    #pragma unroll 8
    for (int c = 0; c < HALF; ++c) {
        float f = xin[(size_t)c << 10];
        float dd = qs[c] - f;                  // fp32(q - f)
        op[(size_t)c << 10] = f + dd;          // fp32(f + fp32(q - f))
        ls += (double)dd * (double)dd;
    }
    #pragma unroll 8
    for (int c = 0; c < HALF; ++c) {
        float f = xin[(size_t)(c + HALF) << 10];
        float dd = qc[c] - f;
        op[(size_t)(c + HALF) << 10] = f + dd;
        ls += (double)dd * (double)dd;
    }

    __shared__ double red[256];
    red[tid] = ls;
    __syncthreads();
    for (int s = 128; s > 0; s >>= 1) {
        if (tid < s) red[tid] += red[tid + s];
        __syncthreads();
    }
    if (tid == 0) atomicAdd(loss_sum, red[0]);
}

__global__ __launch_bounds__(256) void scalars_k(
    const unsigned* __restrict__ cnt_s, const unsigned* __restrict__ cnt_c,
    const double* __restrict__ loss_sum, float* __restrict__ out3)
{
    int tid = threadIdx.x;
    double es = 0.0, ec = 0.0;
    for (int j = tid; j < NSHAPE; j += 256) {
        float p = (float)cnt_s[j] / 32768.0f;
        es += (double)(p * logf(p + 1e-10f));
    }
    for (int j = tid; j < NCOLOR; j += 256) {
        float p = (float)cnt_c[j] / 32768.0f;
        ec += (double)(p * logf(p + 1e-10f));
    }
    __shared__ double r1[256], r2[256];
    r1[tid] = es; r2[tid] = ec;
    __syncthreads();
    for (int s = 128; s > 0; s >>= 1) {
        if (tid < s) { r1[tid] += r1[tid + s]; r2[tid] += r2[tid + s]; }
        __syncthreads();
    }
    if (tid == 0) {
        out3[0] = (float)(1.25 * loss_sum[0] / 8388608.0);  // q + 0.25*e latent
        out3[1] = expf(-(float)r1[0]);
        out3[2] = expf(-(float)r2[0]);
    }
}

extern "C" void kernel_launch(void* const* d_in, const int* in_sizes, int n_in,
                              void* d_out, int out_size, void* d_ws, size_t ws_size,
                              hipStream_t stream)
{
    const float* input = (const float*)d_in[0];
    const float* Ws    = (const float*)d_in[1];
    const float* Wc    = (const float*)d_in[2];
    float* out = (float*)d_out;
    char* ws = (char*)d_ws;

    float*    ts       = (float*)(ws + OFF_TS);
    float*    tcx      = (float*)(ws + OFF_TC);
    unsigned* cnt_s    = (unsigned*)(ws + OFF_CNT_S);
    unsigned* cnt_c    = (unsigned*)(ws + OFF_CNT_C);
    double*   loss_sum = (double*)(ws + OFF_LOSS);
    float*    Ss       = (float*)(ws + OFF_SS);
    float*    Sc       = (float*)(ws + OFF_SC);
    unsigned long long* bs = (unsigned long long*)(ws + OFF_BS);
    unsigned long long* bc = (unsigned long long*)(ws + OFF_BC);

    // counts + loss: zero.  best arrays: 0xFF (== u64 max sentinel).
    hipMemsetAsync(ws + OFF_CNT_S, 0, (OFF_LOSS + 8u) - OFF_CNT_S, stream);
    hipMemsetAsync(ws + OFF_BS, 0xFF, OFF_END - OFF_BS, stream);

    codes_sq_k<<<(NSHAPE + NCOLOR + 255) / 256, 256, 0, stream>>>(Ws, Wc, ts, tcx);
    rows_sq_k<<<NROWS / 256, 256, 0, stream>>>(input, Ss, Sc);

    gemm_argmin_k<<<NBLKS, 256, 0, stream>>>(
        input, Ws, Wc, ts, tcx, Ss, Sc, bs, bc);

    finalize_k<<<NROWS / 256, 256, 0, stream>>>(
        input, Ws, Wc, bs, bc, cnt_s, cnt_c, loss_sum, out);

    scalars_k<<<1, 256, 0, stream>>>(cnt_s, cnt_c, loss_sum, out + 8388608);
}